// Round 5
// baseline (14205.766 us; speedup 1.0000x reference)
//
#include <hip/hip_runtime.h>
#include <hip/hip_bf16.h>
#include <stdint.h>

#define BATCH 1024
#define DIM   1024
#define HID   4096
#define TPTS  16
#define NBLK  512   // persistent grid: 2 blocks/CU x 256 CUs, all co-resident

typedef __attribute__((ext_vector_type(8))) short  short8;
typedef __attribute__((ext_vector_type(4))) float  floatx4;

__device__ __forceinline__ unsigned short f32_to_bf16_bits(float f) {
    union { float f; unsigned u; } v; v.f = f;
    return (unsigned short)((v.u + 0x7fffu + ((v.u >> 16) & 1u)) >> 16);
}

__device__ __forceinline__ void store_bf16x4(unsigned short* p, floatx4 v) {
    union { unsigned short u[4]; uint2 q; } pk;
    pk.u[0] = f32_to_bf16_bits(v[0]);
    pk.u[1] = f32_to_bf16_bits(v[1]);
    pk.u[2] = f32_to_bf16_bits(v[2]);
    pk.u[3] = f32_to_bf16_bits(v[3]);
    *(uint2*)p = pk.q;
}

// fast tanh: 1 - 2/(e^{2x}+1); saturates correctly for |x| large
__device__ __forceinline__ float fast_tanh(float x) {
    float e = __expf(2.0f * x);
    return 1.0f - 2.0f / (e + 1.0f);
}

// async 16B global -> LDS DMA. LDS dest = wave-uniform base + lane*16.
__device__ __forceinline__ void g2l16(const unsigned short* g, char* l) {
    __builtin_amdgcn_global_load_lds(
        (const __attribute__((address_space(1))) void*)g,
        (__attribute__((address_space(3))) void*)l, 16, 0, 0);
}

// R7 persistent-kernel grid barrier. Monotonic counter (no resets; init zeroes
// it each launch/replay). Semantics = what the runtime does between dependent
// dispatches: release(agent)=wbl2 flush of this XCD's dirty L2, then arrive;
// relaxed spin (polls coherence point, NO inv spam while others compute);
// acquire(agent)=buffer_inv on exit. Fences execute at an idle point — unlike
// R5's mid-compute threadfences (which cost 5000us). Mapping-independent:
// correctness never depends on block->XCD assignment; XCD swizzle is perf-only.
__device__ __forceinline__ void gridbar(unsigned* bar, unsigned target) {
    __syncthreads();   // all waves' stores vmcnt-drained (compiler) before arrive
    if (threadIdx.x == 0) {
        __builtin_amdgcn_fence(__ATOMIC_RELEASE, "agent");   // wbl2: flush dirty L2
        __hip_atomic_fetch_add(bar, 1u, __ATOMIC_RELAXED, __HIP_MEMORY_SCOPE_AGENT);
        while (__hip_atomic_load(bar, __ATOMIC_RELAXED, __HIP_MEMORY_SCOPE_AGENT)
               < target)
            __builtin_amdgcn_s_sleep(8);
        __builtin_amdgcn_fence(__ATOMIC_ACQUIRE, "agent");   // inv L1+L2: see fresh
    }
    __syncthreads();
}

// One 64(M) x 128(N) x K=1024 tile, BK=64, 4 waves each 64x32, 2-phase
// double-buffered LDS (2x24KB). Verbatim the R3 K-loop (measured ~920 TF at
// 2 blocks/CU = the 2-barrier-structure ceiling; R4 showed bigger tiles at
// 1 block/CU regress). A row-major bf16 (lda), Bt=B^T row-major (ldb).
__device__ __forceinline__ void gemm_tile(
    const unsigned short* A, const unsigned short* Bt,
    int lda, int ldb, int rowBase, int colBase, long long koff,
    char* smem, floatx4 (&acc)[4][2])
{
    const int tid  = threadIdx.x;
    const int wave = tid >> 6;
    const int lane = tid & 63;
    const int wn = wave * 32;
    const int lr = lane & 15;
    const int q  = lane >> 4;

    // staging: 24KB / (256 thr * 16B) = 6 calls; j=0..1 -> sA, j=2..5 -> sB
    // Row = 8 chunks of 16B; chunk ch holds global k-chunk ch ^ (row & 7).
    const unsigned short* gp[6];
    int lo[6];
#pragma unroll
    for (int j = 0; j < 6; ++j) {
        const int p  = (j * 256 + tid) * 16;
        const int pa = (j < 2) ? p : (p - 8192);
        const int row = pa >> 7;
        const int ch  = (pa >> 4) & 7;
        const int sc  = ch ^ (row & 7);
        if (j < 2)
            gp[j] = A + (long long)(rowBase + row) * lda + koff + sc * 8;
        else
            gp[j] = Bt + (long long)(colBase + row) * ldb + koff + sc * 8;
        lo[j] = p;
    }

#pragma unroll
    for (int mi = 0; mi < 4; ++mi)
#pragma unroll
        for (int ni = 0; ni < 2; ++ni) {
            floatx4 z4 = {0.f, 0.f, 0.f, 0.f};
            acc[mi][ni] = z4;
        }

    const int xr = lr & 7;
    int aOff[4], bOff[2];
#pragma unroll
    for (int i = 0; i < 4; ++i) aOff[i] = (i * 16 + lr) * 128;
#pragma unroll
    for (int i = 0; i < 2; ++i) bOff[i] = (wn + i * 16 + lr) * 128;
    const int swz0 = ((0 + q) ^ xr) * 16;
    const int swz1 = ((4 + q) ^ xr) * 16;

    // prologue: stage K-tile 0 into buffer 0
#pragma unroll
    for (int j = 0; j < 6; ++j)
        g2l16(gp[j], smem + lo[j]);
    __syncthreads();

    int cur = 0;
    for (int kb = 0; kb < 16; ++kb) {        // K = 1024, BK = 64
        if (kb + 1 < 16) {                   // issue next tile's loads first
            const int kadv = (kb + 1) * 64;
            char* nb = smem + (cur ^ 1) * 24576;
#pragma unroll
            for (int j = 0; j < 6; ++j)
                g2l16(gp[j] + kadv, nb + lo[j]);
        }
        const char* sAb = smem + cur * 24576;
        const char* sBb = sAb + 8192;

        short8 af[4][2], bfr[2][2];
#pragma unroll
        for (int i = 0; i < 4; ++i) {
            af[i][0] = *(const short8*)(sAb + aOff[i] + swz0);
            af[i][1] = *(const short8*)(sAb + aOff[i] + swz1);
        }
#pragma unroll
        for (int i = 0; i < 2; ++i) {
            bfr[i][0] = *(const short8*)(sBb + bOff[i] + swz0);
            bfr[i][1] = *(const short8*)(sBb + bOff[i] + swz1);
        }
#pragma unroll
        for (int g = 0; g < 2; ++g)
#pragma unroll
            for (int mi = 0; mi < 4; ++mi)
#pragma unroll
                for (int ni = 0; ni < 2; ++ni)
                    acc[mi][ni] = __builtin_amdgcn_mfma_f32_16x16x32_bf16(
                        af[mi][g], bfr[ni][g], acc[mi][ni], 0, 0, 0);

        __syncthreads();   // drains next tile's loads + protects buffer cur
        cur ^= 1;
    }
}

// R7: the whole 15-step x 4-stage RK4 solve in ONE persistent dispatch.
// 512 blocks (2/CU via __launch_bounds__(256,2) — the guide-sanctioned
// co-residency pattern: grid <= k x 256 with declared occupancy). Per eval:
//   phase1: 512 gemm1 tiles -> Hbf = bf16(tanh(Y@W1+b1))   [R3 MODE1 mapping]
//   phase2: 512 split-K gemm2 tiles -> parts[z]             [R3 MODE0 mapping]
//   phase3: combine (each block 512 float4 of Y-space), RK4 update
// separated by gridbar() (= runtime's inter-dispatch cache semantics without
// the ~2-4us AQL overhead x 180 boundaries). Arithmetic order identical to
// the 3-kernel version -> bitwise-identical trajectory.
__global__ __launch_bounds__(256, 2)
void ode_fused(const unsigned short* W1T, const unsigned short* W2T,
               const float* b1, const float* b2, const float* tspan,
               unsigned short* Ybf, unsigned short* Hbf,
               float* parts, float* kacc, float* out, unsigned* bar)
{
    __shared__ __align__(16) char smem[49152];
    const int tid = threadIdx.x;
    const int bid = (int)blockIdx.x;
    const int wave = tid >> 6;
    const int wn = wave * 32;
    const int lr = (tid & 63) & 15;
    const int q  = (tid & 63) >> 4;

    // XCD-chunked bijective swizzle (perf heuristic only; 512 % 8 == 0)
    const int swz = ((bid & 7) << 6) | (bid >> 3);
    // phase-1 tile: XCD k -> col-groups 4k..4k+3 x all 16 row-groups
    const int cb1 = (swz >> 4) << 7;
    const int rb1 = (swz & 15) << 6;
    // phase-2 tile: XCD pair {2z,2z+1} -> K-slice z; 16 row x 8 col tiles
    const int z2  = swz >> 7;
    const int tl2 = swz & 127;
    const int cb2 = (tl2 & 7) << 7;
    const int rb2 = (tl2 >> 3) << 6;
    // phase-3 slice: 512 consecutive float4 of Y-space per block
    const int iBase = bid << 9;

    float* traj = out + TPTS;
    const int NV4 = BATCH * DIM / 4;
    unsigned tgt = NBLK;
    floatx4 acc[4][2];

    for (int t = 0; t < TPTS - 1; ++t) {
        const float h = tspan[t + 1] - tspan[t];
        const floatx4* yc = (const floatx4*)(traj + (long long)t * BATCH * DIM);
        floatx4* yn = (floatx4*)(traj + (long long)(t + 1) * BATCH * DIM);
        for (int e = 0; e < 4; ++e) {
            // ---------- phase 1: H = bf16(tanh(Y @ W1 + b1)) ----------
            gemm_tile(Ybf, W1T, DIM, DIM, rb1, cb1, 0LL, smem, acc);
            {
                float bias2[2];
#pragma unroll
                for (int ni = 0; ni < 2; ++ni)
                    bias2[ni] = b1[cb1 + wn + ni * 16 + lr];
                unsigned short* sC = (unsigned short*)smem;  // [64][136] bf16
#pragma unroll
                for (int mi = 0; mi < 4; ++mi)
#pragma unroll
                    for (int ni = 0; ni < 2; ++ni)
#pragma unroll
                        for (int r = 0; r < 4; ++r) {
                            const int row = mi * 16 + q * 4 + r;
                            const int col = wn + ni * 16 + lr;
                            sC[row * 136 + col] = f32_to_bf16_bits(
                                fast_tanh(acc[mi][ni][r] + bias2[ni]));
                        }
                __syncthreads();
#pragma unroll
                for (int it = 0; it < 4; ++it) {
                    const int row = it * 16 + (tid >> 4);
                    const int cc  = (tid & 15) * 8;
                    *(uint4*)(Hbf + (long long)(rb1 + row) * HID + cb1 + cc) =
                        *(const uint4*)(sC + row * 136 + cc);
                }
            }
            gridbar(bar, tgt); tgt += NBLK;

            // ---------- phase 2: parts[z] = H[:,z*1024:+1024] @ W2-slice ----------
            gemm_tile(Hbf, W2T, HID, HID, rb2, cb2, (long long)z2 * 1024, smem, acc);
            {
                float* C = parts + (long long)z2 * (BATCH * DIM);
#pragma unroll
                for (int mi = 0; mi < 4; ++mi)
#pragma unroll
                    for (int ni = 0; ni < 2; ++ni) {
                        const int r0 = rb2 + mi * 16 + q * 4;
                        const int c  = cb2 + wn + ni * 16 + lr;
#pragma unroll
                        for (int r = 0; r < 4; ++r)
                            C[(long long)(r0 + r) * DIM + c] = acc[mi][ni][r];
                    }
            }
            gridbar(bar, tgt); tgt += NBLK;

            // ---------- phase 3: k = sum(parts)+b2; RK4 update; next Ybf ----------
            {
                const int mode = e + 1;
                const floatx4* pp = (const floatx4*)parts;
                floatx4* ka = (floatx4*)kacc;
#pragma unroll
                for (int u = 0; u < 2; ++u) {
                    const int i = iBase + tid * 2 + u;
                    // EXACT combine order: p0+p1+p2+p3, then +b2 (bitwise identical)
                    floatx4 k = pp[i] + pp[i + NV4] + pp[i + 2 * NV4] +
                                pp[i + 3 * NV4];
                    k = k + *(const floatx4*)(b2 + ((i * 4) & (DIM - 1)));
                    floatx4 y = yc[i];
                    if (mode == 1) {
                        ka[i] = k;
                        store_bf16x4(Ybf + i * 4, y + (0.5f * h) * k);
                    } else if (mode == 2) {
                        ka[i] = ka[i] + 2.0f * k;
                        store_bf16x4(Ybf + i * 4, y + (0.5f * h) * k);
                    } else if (mode == 3) {
                        ka[i] = ka[i] + 2.0f * k;
                        store_bf16x4(Ybf + i * 4, y + h * k);
                    } else {
                        floatx4 ynv = y + (h * (1.0f / 6.0f)) * (ka[i] + k);
                        yn[i] = ynv;
                        store_bf16x4(Ybf + i * 4, ynv);
                    }
                }
            }
            if (!(t == TPTS - 2 && e == 3)) { gridbar(bar, tgt); tgt += NBLK; }
        }
    }
}

// out[c][r] = bf16(in[r][c]); in is R x C fp32.
__global__ void transpose_cast(const float* __restrict__ in,
                               unsigned short* __restrict__ out, int R, int C)
{
    __shared__ float tile[32][33];
    const int bx = blockIdx.x * 32;
    const int by = blockIdx.y * 32;
    const int tx = threadIdx.x, ty = threadIdx.y;  // (32, 8)
#pragma unroll
    for (int i = 0; i < 4; ++i)
        tile[ty + i * 8][tx] = in[(long long)(by + ty + i * 8) * C + bx + tx];
    __syncthreads();
#pragma unroll
    for (int i = 0; i < 4; ++i)
        out[(long long)(bx + ty + i * 8) * R + by + tx] =
            f32_to_bf16_bits(tile[tx][ty + i * 8]);
}

// d_out[0:16] = t_span; traj[0] = y_init; ybf = bf16(y_init); zero barrier ctr
__global__ void init_kernel(const float* __restrict__ y0,
                            const float* __restrict__ tspan,
                            float* __restrict__ out,
                            unsigned short* __restrict__ ybf,
                            unsigned int* __restrict__ bar)
{
    const int i = blockIdx.x * blockDim.x + threadIdx.x;
    floatx4 v = ((const floatx4*)y0)[i];
    ((floatx4*)(out + TPTS))[i] = v;
    store_bf16x4(ybf + i * 4, v);
    if (blockIdx.x == 0 && threadIdx.x < TPTS) out[threadIdx.x] = tspan[threadIdx.x];
    if (blockIdx.x == 1 && threadIdx.x == 0) *bar = 0u;
}

extern "C" void kernel_launch(void* const* d_in, const int* in_sizes, int n_in,
                              void* d_out, int out_size, void* d_ws, size_t ws_size,
                              hipStream_t stream)
{
    (void)in_sizes; (void)n_in; (void)out_size; (void)ws_size;
    const float* y0    = (const float*)d_in[0];
    const float* tspan = (const float*)d_in[1];
    const float* W1    = (const float*)d_in[2];
    const float* b1    = (const float*)d_in[3];
    const float* W2    = (const float*)d_in[4];
    const float* b2    = (const float*)d_in[5];
    float* out = (float*)d_out;

    char* ws = (char*)d_ws;
    unsigned short* W1T = (unsigned short*)(ws);                // [HID][DIM] bf16   8MB
    unsigned short* W2T = (unsigned short*)(ws + (8ll << 20));  // [DIM][HID] bf16   8MB
    unsigned short* Ybf = (unsigned short*)(ws + (16ll << 20)); // [BATCH][DIM] bf16 2MB
    unsigned short* Hbf = (unsigned short*)(ws + (18ll << 20)); // [BATCH][HID] bf16 8MB
    float* parts = (float*)(ws + (26ll << 20));                 // [4][BATCH][DIM]  16MB
    float* kacc  = (float*)(ws + (42ll << 20));                 // [BATCH][DIM]      4MB
    unsigned int* bar = (unsigned int*)(ws + (46ll << 20));     // barrier counter

    dim3 tb(32, 8);
    transpose_cast<<<dim3(HID / 32, DIM / 32), tb, 0, stream>>>(W1, W1T, DIM, HID);
    transpose_cast<<<dim3(DIM / 32, HID / 32), tb, 0, stream>>>(W2, W2T, HID, DIM);
    init_kernel<<<BATCH * DIM / 1024, 256, 0, stream>>>(y0, tspan, out, Ybf, bar);

    // whole solve: one persistent dispatch, 179 grid barriers
    ode_fused<<<NBLK, 256, 0, stream>>>(W1T, W2T, b1, b2, tspan,
                                        Ybf, Hbf, parts, kacc, out, bar);
}

// Round 6
// 3563.028 us; speedup vs baseline: 3.9870x; 3.9870x over previous
//
#include <hip/hip_runtime.h>
#include <hip/hip_bf16.h>
#include <stdint.h>

#define BATCH 1024
#define DIM   1024
#define HID   4096
#define TPTS  16
#define NBLK  512   // 2 blocks/CU x 256 CUs, co-resident (launch_bounds(256,2))

typedef __attribute__((ext_vector_type(8))) short  short8;
typedef __attribute__((ext_vector_type(4))) float  floatx4;
typedef __attribute__((ext_vector_type(2))) unsigned long long u64x2;

__device__ __forceinline__ unsigned short f32_to_bf16_bits(float f) {
    union { float f; unsigned u; } v; v.f = f;
    return (unsigned short)((v.u + 0x7fffu + ((v.u >> 16) & 1u)) >> 16);
}

__device__ __forceinline__ void store_bf16x4(unsigned short* p, floatx4 v) {
    union { unsigned short u[4]; uint2 q; } pk;
    pk.u[0] = f32_to_bf16_bits(v[0]);
    pk.u[1] = f32_to_bf16_bits(v[1]);
    pk.u[2] = f32_to_bf16_bits(v[2]);
    pk.u[3] = f32_to_bf16_bits(v[3]);
    *(uint2*)p = pk.q;
}

// bf16x4 pack + relaxed SYSTEM-scope store: global_store_dwordx2 sc0 sc1 =
// write-THROUGH to the coherence point. Nothing dirty left in any L2 -> no
// flush ever needed for cross-XCD visibility. (Pattern validated in R6.)
__device__ __forceinline__ void st_sys_bf16x4(unsigned short* p, floatx4 v) {
    union { unsigned short u[4]; unsigned long long q; } pk;
    pk.u[0] = f32_to_bf16_bits(v[0]);
    pk.u[1] = f32_to_bf16_bits(v[1]);
    pk.u[2] = f32_to_bf16_bits(v[2]);
    pk.u[3] = f32_to_bf16_bits(v[3]);
    __hip_atomic_store((unsigned long long*)p, pk.q,
                       __ATOMIC_RELAXED, __HIP_MEMORY_SCOPE_SYSTEM);
}

// 16B coherence-point load (sc0 sc1: bypasses L1 AND the per-XCD L2, which
// may hold stale Ybf lines from a previous eval). Two 8B atomic loads.
__device__ __forceinline__ u64x2 ld_sys16b(const unsigned short* p) {
    u64x2 r;
    r.x = __hip_atomic_load((const unsigned long long*)p,
                            __ATOMIC_RELAXED, __HIP_MEMORY_SCOPE_SYSTEM);
    r.y = __hip_atomic_load((const unsigned long long*)p + 1,
                            __ATOMIC_RELAXED, __HIP_MEMORY_SCOPE_SYSTEM);
    return r;
}

// fast tanh: 1 - 2/(e^{2x}+1); saturates correctly for |x| large
__device__ __forceinline__ float fast_tanh(float x) {
    float e = __expf(2.0f * x);
    return 1.0f - 2.0f / (e + 1.0f);
}

// async 16B global -> LDS DMA. LDS dest = wave-uniform base + lane*16.
__device__ __forceinline__ void g2l16(const unsigned short* g, char* l) {
    __builtin_amdgcn_global_load_lds(
        (const __attribute__((address_space(1))) void*)g,
        (__attribute__((address_space(3))) void*)l, 16, 0, 0);
}

// ============================================================================
// g1_fused: [phase A: combine(prev eval)] -> counter barrier -> [phase B: gemm1]
//
// R7 POST-MORTEM: __builtin_amdgcn_fence(agent) = per-block buffer_wbl2/inv
// pushed data to HBM and cold-started every phase (6.6GB HBM fetch, 14.2ms).
// NO fence instructions anywhere. This kernel uses only the R6-validated
// fence-free pattern: Ybf written via relaxed-SYSTEM write-through stores;
// __syncthreads() drains vmcnt (compiler emits s_waitcnt vmcnt(0) before
// s_barrier) -> stores globally visible before tid0's relaxed agent
// atomicAdd; spin on monotonic counter (target passed as arg, init zeroes
// the counter each replay); phase B reads Ybf ONLY via sc0+sc1 loads
// (bypass possibly-stale L1/L2). All other arrays (parts, kacc, traj, W1T,
// Hbf) cross dispatch boundaries only -> plain ops + runtime maintenance.
// Correct independent of block->XCD mapping (swizzle stays perf-only).
//
// Phase B = R3's measured-best gemm core (64x128 tile, BK=64, 4 waves of
// 64x32, 2-phase double-buffered 2x24KB LDS, 2 blocks/CU, ~920 TF), with
// A-staging switched to per-lane sc1 loads + ds_write_b128 (B stays DMA).
// Phase A math = combine kernel verbatim -> bitwise-identical trajectory.
// ============================================================================
__global__ __launch_bounds__(256, 2)
void g1_fused(const unsigned short* __restrict__ W1T,
              const float* __restrict__ b1,
              const float* __restrict__ b2,
              const float* __restrict__ tspan,
              unsigned short* __restrict__ Ybf,
              unsigned short* __restrict__ Hbf,
              const float* __restrict__ parts,
              float* __restrict__ kacc,
              float* __restrict__ traj,
              unsigned* __restrict__ bar,
              unsigned tgt, int cstep, int cmode)
{
    __shared__ __align__(16) char smem[49152];
    const int tid  = threadIdx.x;
    const int bid  = (int)blockIdx.x;

    // ---------------- phase A: combine for previous eval (cmode 1..4) -------
    if (cmode) {
        const float h = tspan[cstep + 1] - tspan[cstep];
        const floatx4* pp = (const floatx4*)parts;
        const floatx4* yc = (const floatx4*)(traj + (long long)cstep * BATCH * DIM);
        floatx4* yn = (floatx4*)(traj + (long long)(cstep + 1) * BATCH * DIM);
        floatx4* ka = (floatx4*)kacc;
        const int NV4 = BATCH * DIM / 4;
#pragma unroll
        for (int u = 0; u < 2; ++u) {
            const int i = (bid << 9) + tid * 2 + u;   // 512 f4 per block
            // EXACT combine order: p0+p1+p2+p3, then +b2 (bitwise identical)
            floatx4 k = pp[i] + pp[i + NV4] + pp[i + 2 * NV4] + pp[i + 3 * NV4];
            k = k + *(const floatx4*)(b2 + ((i * 4) & (DIM - 1)));
            floatx4 y = yc[i];
            floatx4 ynew;
            if (cmode == 1)      { ka[i] = k;               ynew = y + (0.5f * h) * k; }
            else if (cmode == 2) { ka[i] = ka[i] + 2.0f * k; ynew = y + (0.5f * h) * k; }
            else if (cmode == 3) { ka[i] = ka[i] + 2.0f * k; ynew = y + h * k; }
            else { ynew = y + (h * (1.0f / 6.0f)) * (ka[i] + k); yn[i] = ynew; }
            st_sys_bf16x4(Ybf + i * 4, ynew);   // write-through, no fence
        }
        // fence-free grid barrier: syncthreads drains this block's sc1 stores
        // (vmcnt(0)) before tid0 arrives at the counter.
        __syncthreads();
        if (tid == 0) {
            __hip_atomic_fetch_add(bar, 1u, __ATOMIC_RELAXED,
                                   __HIP_MEMORY_SCOPE_AGENT);
            while (__hip_atomic_load(bar, __ATOMIC_RELAXED,
                                     __HIP_MEMORY_SCOPE_AGENT) < tgt)
                __builtin_amdgcn_s_sleep(2);
        }
        __syncthreads();
        asm volatile("" ::: "memory");   // no compiler reordering across barrier
    }

    // ---------------- phase B: H = bf16(tanh(Y @ W1 + b1)) ------------------
    const int wave = tid >> 6;
    const int lane = tid & 63;
    const int wn = wave * 32;
    const int lr = lane & 15;
    const int q  = lane >> 4;

    // XCD-chunked bijective swizzle (perf-only; 512 % 8 == 0): XCD k owns
    // col-groups 4k..4k+3 x all 16 row-groups (W1T panel 1MB + stays L2-warm).
    const int swz = ((bid & 7) << 6) | (bid >> 3);
    const int colBase = (swz >> 4) << 7;
    const int rowBase = (swz & 15) << 6;

    // staging map: 24KB/buffer; A (Ybf) = j0..1 reg-staged sc1; B (W1T) = j2..5 DMA.
    // Row = 8 chunks of 16B; chunk ch holds global k-chunk ch ^ (row & 7).
    const unsigned short* gpA[2]; const unsigned short* gpB[4];
    int loA[2], loB[4];
#pragma unroll
    for (int j = 0; j < 6; ++j) {
        const int p  = (j * 256 + tid) * 16;
        const int pa = (j < 2) ? p : (p - 8192);
        const int row = pa >> 7;
        const int ch  = (pa >> 4) & 7;
        const int sc  = ch ^ (row & 7);
        if (j < 2) { gpA[j] = Ybf + (long long)(rowBase + row) * DIM + sc * 8; loA[j] = p; }
        else { gpB[j - 2] = W1T + (long long)(colBase + row) * DIM + sc * 8; loB[j - 2] = p; }
    }

    floatx4 acc[4][2];
#pragma unroll
    for (int mi = 0; mi < 4; ++mi)
#pragma unroll
        for (int ni = 0; ni < 2; ++ni) {
            floatx4 z4 = {0.f, 0.f, 0.f, 0.f};
            acc[mi][ni] = z4;
        }

    const int xr = lr & 7;
    int aOff[4], bOff[2];
#pragma unroll
    for (int i = 0; i < 4; ++i) aOff[i] = (i * 16 + lr) * 128;
#pragma unroll
    for (int i = 0; i < 2; ++i) bOff[i] = (wn + i * 16 + lr) * 128;
    const int swz0 = ((0 + q) ^ xr) * 16;
    const int swz1 = ((4 + q) ^ xr) * 16;

    // prologue: stage K-tile 0 into buffer 0
    u64x2 a0 = ld_sys16b(gpA[0]);
    u64x2 a1 = ld_sys16b(gpA[1]);
#pragma unroll
    for (int j = 0; j < 4; ++j) g2l16(gpB[j], smem + loB[j]);
    *(u64x2*)(smem + loA[0]) = a0;
    *(u64x2*)(smem + loA[1]) = a1;
    __syncthreads();

    int cur = 0;
    for (int kb = 0; kb < 16; ++kb) {      // K = DIM = 1024, BK = 64
        u64x2 na0, na1;
        char* nb = smem + (cur ^ 1) * 24576;
        if (kb + 1 < 16) {                 // issue next tile's loads first
            const int kadv = (kb + 1) * 64;
            na0 = ld_sys16b(gpA[0] + kadv);       // sc1: fresh Ybf from MALL
            na1 = ld_sys16b(gpA[1] + kadv);
#pragma unroll
            for (int j = 0; j < 4; ++j) g2l16(gpB[j] + kadv, nb + loB[j]);
        }
        const char* sAb = smem + cur * 24576;
        const char* sBb = sAb + 8192;

        short8 af[4][2], bfr[2][2];
#pragma unroll
        for (int i = 0; i < 4; ++i) {
            af[i][0] = *(const short8*)(sAb + aOff[i] + swz0);
            af[i][1] = *(const short8*)(sAb + aOff[i] + swz1);
        }
#pragma unroll
        for (int i = 0; i < 2; ++i) {
            bfr[i][0] = *(const short8*)(sBb + bOff[i] + swz0);
            bfr[i][1] = *(const short8*)(sBb + bOff[i] + swz1);
        }
#pragma unroll
        for (int g = 0; g < 2; ++g)
#pragma unroll
            for (int mi = 0; mi < 4; ++mi)
#pragma unroll
                for (int ni = 0; ni < 2; ++ni)
                    acc[mi][ni] = __builtin_amdgcn_mfma_f32_16x16x32_bf16(
                        af[mi][g], bfr[ni][g], acc[mi][ni], 0, 0, 0);

        if (kb + 1 < 16) {                 // land A regs into next buffer
            *(u64x2*)(nb + loA[0]) = na0;
            *(u64x2*)(nb + loA[1]) = na1;
        }
        __syncthreads();                   // drains DMA + protects buffer cur
        cur ^= 1;
    }

    // epilogue: bias + tanh + bf16, coalesced store via LDS restage
    float bias2[2];
#pragma unroll
    for (int ni = 0; ni < 2; ++ni)
        bias2[ni] = b1[colBase + wn + ni * 16 + lr];
    unsigned short* sC = (unsigned short*)smem;  // [64][136] bf16
#pragma unroll
    for (int mi = 0; mi < 4; ++mi)
#pragma unroll
        for (int ni = 0; ni < 2; ++ni)
#pragma unroll
            for (int r = 0; r < 4; ++r) {
                const int row = mi * 16 + q * 4 + r;
                const int col = wn + ni * 16 + lr;
                sC[row * 136 + col] =
                    f32_to_bf16_bits(fast_tanh(acc[mi][ni][r] + bias2[ni]));
            }
    __syncthreads();
#pragma unroll
    for (int it = 0; it < 4; ++it) {
        const int row = it * 16 + (tid >> 4);
        const int cc  = (tid & 15) * 8;
        *(uint4*)(Hbf + (long long)(rowBase + row) * HID + colBase + cc) =
            *(const uint4*)(sC + row * 136 + cc);
    }
}

// ============================================================================
// gemm2_bt: parts[z] = Hbf[:, z*1024:+1024] @ W2slice (exactly R3's MODE 0).
// grid (8,16,4) = 512 blocks, 2/CU. Plain fp32 partial stores, no fences,
// no atomics — parts crosses a dispatch boundary (runtime maintenance).
// ============================================================================
__global__ __launch_bounds__(256, 2)
void gemm2_bt(const unsigned short* __restrict__ A,   // Hbf [BATCH][HID]
              const unsigned short* __restrict__ Bt,  // W2T [DIM][HID]
              float* __restrict__ Cout)               // parts [4][BATCH][DIM]
{
    __shared__ __align__(16) char smem[49152];
    const int tid  = threadIdx.x;
    const int wave = tid >> 6;
    const int lane = tid & 63;
    const int wn = wave * 32;
    const int lr = lane & 15;
    const int q  = lane >> 4;

    const int lin = (int)blockIdx.x +
                    (((int)blockIdx.y + ((int)blockIdx.z << 4)) << 3);
    const int swz = ((lin & 7) << 6) | (lin >> 3);
    const int zIdx  = swz >> 7;            // XCDs {2z,2z+1} share K-slice z
    const int tileS = swz & 127;
    const int colBase = (tileS & 7) << 7;
    const int rowBase = (tileS >> 3) << 6;
    const long long koff = (long long)zIdx * 1024;

    const unsigned short* gp[6];
    int lo[6];
#pragma unroll
    for (int j = 0; j < 6; ++j) {
        const int p  = (j * 256 + tid) * 16;
        const int pa = (j < 2) ? p : (p - 8192);
        const int row = pa >> 7;
        const int ch  = (pa >> 4) & 7;
        const int sc  = ch ^ (row & 7);
        if (j < 2)
            gp[j] = A + (long long)(rowBase + row) * HID + koff + sc * 8;
        else
            gp[j] = Bt + (long long)(colBase + row) * HID + koff + sc * 8;
        lo[j] = p;
    }

    floatx4 acc[4][2];
#pragma unroll
    for (int mi = 0; mi < 4; ++mi)
#pragma unroll
        for (int ni = 0; ni < 2; ++ni) {
            floatx4 z4 = {0.f, 0.f, 0.f, 0.f};
            acc[mi][ni] = z4;
        }

    const int xr = lr & 7;
    int aOff[4], bOff[2];
#pragma unroll
    for (int i = 0; i < 4; ++i) aOff[i] = (i * 16 + lr) * 128;
#pragma unroll
    for (int i = 0; i < 2; ++i) bOff[i] = (wn + i * 16 + lr) * 128;
    const int swz0 = ((0 + q) ^ xr) * 16;
    const int swz1 = ((4 + q) ^ xr) * 16;

#pragma unroll
    for (int j = 0; j < 6; ++j)
        g2l16(gp[j], smem + lo[j]);
    __syncthreads();

    int cur = 0;
    for (int kb = 0; kb < 16; ++kb) {
        if (kb + 1 < 16) {
            const int kadv = (kb + 1) * 64;
            char* nb = smem + (cur ^ 1) * 24576;
#pragma unroll
            for (int j = 0; j < 6; ++j)
                g2l16(gp[j] + kadv, nb + lo[j]);
        }
        const char* sAb = smem + cur * 24576;
        const char* sBb = sAb + 8192;

        short8 af[4][2], bfr[2][2];
#pragma unroll
        for (int i = 0; i < 4; ++i) {
            af[i][0] = *(const short8*)(sAb + aOff[i] + swz0);
            af[i][1] = *(const short8*)(sAb + aOff[i] + swz1);
        }
#pragma unroll
        for (int i = 0; i < 2; ++i) {
            bfr[i][0] = *(const short8*)(sBb + bOff[i] + swz0);
            bfr[i][1] = *(const short8*)(sBb + bOff[i] + swz1);
        }
#pragma unroll
        for (int g = 0; g < 2; ++g)
#pragma unroll
            for (int mi = 0; mi < 4; ++mi)
#pragma unroll
                for (int ni = 0; ni < 2; ++ni)
                    acc[mi][ni] = __builtin_amdgcn_mfma_f32_16x16x32_bf16(
                        af[mi][g], bfr[ni][g], acc[mi][ni], 0, 0, 0);

        __syncthreads();
        cur ^= 1;
    }

    float* C = Cout + (long long)zIdx * (BATCH * DIM);
#pragma unroll
    for (int mi = 0; mi < 4; ++mi)
#pragma unroll
        for (int ni = 0; ni < 2; ++ni) {
            const int r0 = rowBase + mi * 16 + q * 4;
            const int c  = colBase + wn + ni * 16 + lr;
#pragma unroll
            for (int r = 0; r < 4; ++r)
                C[(long long)(r0 + r) * DIM + c] = acc[mi][ni][r];
        }
}

// standalone combine — used once for the FINAL eval (step 14, mode 4).
__global__ void combine(const float* __restrict__ parts,
                        const float* __restrict__ b2,
                        const float* __restrict__ ycur,
                        const float* __restrict__ tspan,
                        int step, int mode,
                        float* __restrict__ kacc,
                        unsigned short* __restrict__ ybf,
                        float* __restrict__ ynext)
{
    const int i = blockIdx.x * blockDim.x + threadIdx.x;
    const float h = tspan[step + 1] - tspan[step];
    const int NV = BATCH * DIM / 4;
    const floatx4* p = (const floatx4*)parts;
    floatx4 k = p[i] + p[i + NV] + p[i + 2 * NV] + p[i + 3 * NV];
    k = k + *(const floatx4*)(b2 + ((i * 4) & (DIM - 1)));
    floatx4 y = ((const floatx4*)ycur)[i];
    floatx4* ka = (floatx4*)kacc;
    if (mode == 4) {
        floatx4 yn = y + (h * (1.0f / 6.0f)) * (ka[i] + k);
        ((floatx4*)ynext)[i] = yn;
        store_bf16x4(ybf + i * 4, yn);
    }
}

// out[c][r] = bf16(in[r][c]); in is R x C fp32.
__global__ void transpose_cast(const float* __restrict__ in,
                               unsigned short* __restrict__ out, int R, int C)
{
    __shared__ float tile[32][33];
    const int bx = blockIdx.x * 32;
    const int by = blockIdx.y * 32;
    const int tx = threadIdx.x, ty = threadIdx.y;  // (32, 8)
#pragma unroll
    for (int i = 0; i < 4; ++i)
        tile[ty + i * 8][tx] = in[(long long)(by + ty + i * 8) * C + bx + tx];
    __syncthreads();
#pragma unroll
    for (int i = 0; i < 4; ++i)
        out[(long long)(bx + ty + i * 8) * R + by + tx] =
            f32_to_bf16_bits(tile[tx][ty + i * 8]);
}

// d_out[0:16] = t_span; traj[0] = y_init; ybf = bf16(y_init); zero barrier ctr
__global__ void init_kernel(const float* __restrict__ y0,
                            const float* __restrict__ tspan,
                            float* __restrict__ out,
                            unsigned short* __restrict__ ybf,
                            unsigned int* __restrict__ bar)
{
    const int i = blockIdx.x * blockDim.x + threadIdx.x;
    floatx4 v = ((const floatx4*)y0)[i];
    ((floatx4*)(out + TPTS))[i] = v;
    store_bf16x4(ybf + i * 4, v);
    if (blockIdx.x == 0 && threadIdx.x < TPTS) out[threadIdx.x] = tspan[threadIdx.x];
    if (blockIdx.x == 1 && threadIdx.x == 0) *bar = 0u;
}

extern "C" void kernel_launch(void* const* d_in, const int* in_sizes, int n_in,
                              void* d_out, int out_size, void* d_ws, size_t ws_size,
                              hipStream_t stream)
{
    (void)in_sizes; (void)n_in; (void)out_size; (void)ws_size;
    const float* y0    = (const float*)d_in[0];
    const float* tspan = (const float*)d_in[1];
    const float* W1    = (const float*)d_in[2];
    const float* b1    = (const float*)d_in[3];
    const float* W2    = (const float*)d_in[4];
    const float* b2    = (const float*)d_in[5];
    float* out = (float*)d_out;

    char* ws = (char*)d_ws;
    unsigned short* W1T = (unsigned short*)(ws);                // [HID][DIM] bf16   8MB
    unsigned short* W2T = (unsigned short*)(ws + (8ll << 20));  // [DIM][HID] bf16   8MB
    unsigned short* Ybf = (unsigned short*)(ws + (16ll << 20)); // [BATCH][DIM] bf16 2MB
    unsigned short* Hbf = (unsigned short*)(ws + (18ll << 20)); // [BATCH][HID] bf16 8MB
    float* parts = (float*)(ws + (26ll << 20));                 // [4][BATCH][DIM]  16MB
    float* kacc  = (float*)(ws + (42ll << 20));                 // [BATCH][DIM]      4MB
    unsigned int* bar = (unsigned int*)(ws + (46ll << 20));     // barrier counter

    dim3 tb(32, 8);
    transpose_cast<<<dim3(HID / 32, DIM / 32), tb, 0, stream>>>(W1, W1T, DIM, HID);
    transpose_cast<<<dim3(DIM / 32, HID / 32), tb, 0, stream>>>(W2, W2T, HID, DIM);
    init_kernel<<<BATCH * DIM / 1024, 256, 0, stream>>>(y0, tspan, out, Ybf, bar);

    float* traj = out + TPTS;
    unsigned k = 0;
    for (int t = 0; t < TPTS - 1; ++t) {
        for (int e = 0; e < 4; ++e) {
            const int cmode = (k == 0) ? 0 : (int)(((k - 1) & 3u) + 1u);
            const int cstep = (k == 0) ? 0 : (int)((k - 1) >> 2);
            // [combine(prev eval) -> fence-free barrier ->] gemm1
            g1_fused<<<NBLK, 256, 0, stream>>>(W1T, b1, b2, tspan, Ybf, Hbf,
                                               parts, kacc, traj, bar,
                                               k * NBLK, cstep, cmode);
            // parts[z] = H[:,z*1024:+1024] @ W2-slice
            gemm2_bt<<<dim3(8, 16, 4), 256, 0, stream>>>(Hbf, W2T, parts);
            ++k;
        }
    }
    // final eval's combine (step 14, mode 4) -> traj[15]
    combine<<<BATCH * DIM / 1024, 256, 0, stream>>>(
        parts, b2, traj + 14LL * BATCH * DIM, tspan, 14, 4, kacc, Ybf,
        traj + 15LL * BATCH * DIM);
}